// Round 1
// baseline (226.570 us; speedup 1.0000x reference)
//
#include <hip/hip_runtime.h>

// EdgeLoss: mean |sobel_mag(gray(pred)) - sobel_mag(gray(target))|
// pred/target: (32, 3, 512, 512) fp32, output: scalar fp32.
// Memory-bound: 201 MB read once -> ~32 us floor at 6.3 TB/s.
//
// R2 -> R3: rocprof showed VGPR_Count=16 -> regalloc serialized the "6
// independent" staging loads into a load->waitcnt->use chain (~1-2 in
// flight/wave) -> 2.3 TB/s, latency-bound. Now: all 18 float4 loads (3 trips
// x 6) are issued into named registers up front, with sched_barrier(0)
// pinning every use below the loads. This forces >=72 live VGPRs of load
// results -> 18-deep MLP per wave. __launch_bounds__(256,4) budgets 128
// VGPRs (16 waves/CU); 16 waves x 18 loads >> the ~9 outstanding
// wave-loads/CU needed to saturate HBM.
// Compute phase is byte-identical to R2 (absmax was 0.0 - math untouched).

#define BATCH 32
#define HH 512
#define WW 512
#define TX 64
#define TY 32
#define LDS_W 72                  // floats per staged row (x0-4 .. x0+67)
#define LDS_W4 18                 // float4 per staged row
#define LDS_ROWS 34               // y0-1 .. y0+32
#define SLOTS (LDS_ROWS * LDS_W4) // 612 float4 slots per image

__global__ void zero_out_kernel(float* out) { out[0] = 0.0f; }

#define GRAY4(D, R, G, B)                              \
    do {                                               \
        D.x = 0.299f * R.x + 0.587f * G.x + 0.114f * B.x; \
        D.y = 0.299f * R.y + 0.587f * G.y + 0.114f * B.y; \
        D.z = 0.299f * R.z + 0.587f * G.z + 0.114f * B.z; \
        D.w = 0.299f * R.w + 0.587f * G.w + 0.114f * B.w; \
    } while (0)

__global__ __launch_bounds__(256, 4) void edge_loss_kernel(
    const float* __restrict__ pred,
    const float* __restrict__ target,
    float* __restrict__ out)
{
    __shared__ float gp[LDS_ROWS * LDS_W];
    __shared__ float gt[LDS_ROWS * LDS_W];

    const int tid = threadIdx.x;
    const int x0 = blockIdx.x * TX;
    const int y0 = blockIdx.y * TY;
    const int b  = blockIdx.z;

    const size_t img = (size_t)HH * WW;
    const float* pbase = pred   + (size_t)b * 3 * img;
    const float* tbase = target + (size_t)b * 3 * img;

    float4* gp4 = (float4*)gp;
    float4* gt4 = (float4*)gt;

    // ---- Trip metadata: slot -> (row, col) -> global offset + in-bounds ----
    int  off[3];
    bool ok[3];
    #pragma unroll
    for (int t = 0; t < 3; ++t) {
        const int i   = tid + t * 256;
        const int row = i / LDS_W4;          // 0..33 (garbage rows masked by ok)
        const int c   = i - row * LDS_W4;    // 0..17
        const int gy  = y0 - 1 + row;
        const int gx  = x0 - 4 + 4 * c;
        ok[t]  = (i < SLOTS) & (gy >= 0) & (gy < HH) & (gx >= 0) & (gx <= WW - 4);
        off[t] = gy * WW + gx;
    }

    // ---- Issue ALL 18 float4 loads before any use (forced 18-deep MLP) ----
    float4 pr0, pg0, pb0, tr0, tg0, tb0;
    float4 pr1, pg1, pb1, tr1, tg1, tb1;
    float4 pr2, pg2, pb2, tr2, tg2, tb2;
    if (ok[0]) {
        const size_t o = (size_t)off[0];
        pr0 = *(const float4*)(pbase + o);
        pg0 = *(const float4*)(pbase + o + img);
        pb0 = *(const float4*)(pbase + o + 2 * img);
        tr0 = *(const float4*)(tbase + o);
        tg0 = *(const float4*)(tbase + o + img);
        tb0 = *(const float4*)(tbase + o + 2 * img);
    }
    if (ok[1]) {
        const size_t o = (size_t)off[1];
        pr1 = *(const float4*)(pbase + o);
        pg1 = *(const float4*)(pbase + o + img);
        pb1 = *(const float4*)(pbase + o + 2 * img);
        tr1 = *(const float4*)(tbase + o);
        tg1 = *(const float4*)(tbase + o + img);
        tb1 = *(const float4*)(tbase + o + 2 * img);
    }
    if (ok[2]) {
        const size_t o = (size_t)off[2];
        pr2 = *(const float4*)(pbase + o);
        pg2 = *(const float4*)(pbase + o + img);
        pb2 = *(const float4*)(pbase + o + 2 * img);
        tr2 = *(const float4*)(tbase + o);
        tg2 = *(const float4*)(tbase + o + img);
        tb2 = *(const float4*)(tbase + o + 2 * img);
    }
    // Nothing crosses this point: loads stay issued above, uses stay below.
    __builtin_amdgcn_sched_barrier(0);

    // ---- Grayscale + LDS store per trip ----
#define STORE_TRIP(T, PR, PG, PB, TR, TG, TB)              \
    do {                                                   \
        const int i = tid + T * 256;                       \
        if (i < SLOTS) {                                   \
            float4 vp = make_float4(0.f, 0.f, 0.f, 0.f);   \
            float4 vt = make_float4(0.f, 0.f, 0.f, 0.f);   \
            if (ok[T]) {                                   \
                GRAY4(vp, PR, PG, PB);                     \
                GRAY4(vt, TR, TG, TB);                     \
            }                                              \
            gp4[i] = vp;                                   \
            gt4[i] = vt;                                   \
        }                                                  \
    } while (0)

    STORE_TRIP(0, pr0, pg0, pb0, tr0, tg0, tb0);
    STORE_TRIP(1, pr1, pg1, pb1, tr1, tg1, tb1);
    STORE_TRIP(2, pr2, pg2, pb2, tr2, tg2, tb2);
#undef STORE_TRIP

    __syncthreads();

    // ---- Compute: 64 wide x 4 tall, each thread does 8 rows (unchanged) ----
    const int tx = tid & 63;
    const int ty = tid >> 6;
    float lsum = 0.0f;

    #pragma unroll
    for (int i = 0; i < TY / 4; ++i) {
        const int ry = ty + 4 * i;                     // output row within tile
        const float* cp = &gp[ry * LDS_W + tx + 3];    // window top-left
        const float* ct = &gt[ry * LDS_W + tx + 3];

        float p00 = cp[0],         p01 = cp[1],             p02 = cp[2];
        float p10 = cp[LDS_W],                              p12 = cp[LDS_W + 2];
        float p20 = cp[2*LDS_W],   p21 = cp[2*LDS_W + 1],   p22 = cp[2*LDS_W + 2];
        float ex = (p02 - p00) + 2.0f * (p12 - p10) + (p22 - p20);
        float ey = (p20 - p00) + 2.0f * (p21 - p01) + (p22 - p02);
        float ep = sqrtf(ex * ex + ey * ey);

        float t00 = ct[0],         t01 = ct[1],             t02 = ct[2];
        float t10 = ct[LDS_W],                              t12 = ct[LDS_W + 2];
        float t20 = ct[2*LDS_W],   t21 = ct[2*LDS_W + 1],   t22 = ct[2*LDS_W + 2];
        float fx = (t02 - t00) + 2.0f * (t12 - t10) + (t22 - t20);
        float fy = (t20 - t00) + 2.0f * (t21 - t01) + (t22 - t02);
        float et = sqrtf(fx * fx + fy * fy);

        lsum += fabsf(ep - et);
    }

    // ---- Reduce: wave shuffle -> cross-wave LDS -> one atomic per block ----
    #pragma unroll
    for (int off_ = 32; off_ > 0; off_ >>= 1)
        lsum += __shfl_down(lsum, off_, 64);

    __shared__ float wsum[4];
    if ((tid & 63) == 0) wsum[ty] = lsum;
    __syncthreads();
    if (tid == 0) {
        const float s = wsum[0] + wsum[1] + wsum[2] + wsum[3];
        const float inv_n = 1.0f / ((float)BATCH * HH * WW);
        atomicAdd(out, s * inv_n);
    }
}

extern "C" void kernel_launch(void* const* d_in, const int* in_sizes, int n_in,
                              void* d_out, int out_size, void* d_ws, size_t ws_size,
                              hipStream_t stream) {
    const float* pred   = (const float*)d_in[0];
    const float* target = (const float*)d_in[1];
    float* out = (float*)d_out;

    // d_out is poisoned 0xAA before every timed launch -> zero it on-stream.
    zero_out_kernel<<<1, 1, 0, stream>>>(out);

    dim3 grid(WW / TX, HH / TY, BATCH);  // (8, 16, 32) = 4096 blocks
    edge_loss_kernel<<<grid, 256, 0, stream>>>(pred, target, out);
}